// Round 2
// 462.761 us; speedup vs baseline: 1.0121x; 1.0121x over previous
//
#include <hip/hip_runtime.h>
#include <cstdint>
#include <cstddef>

#define N_NODES_C 100000
#define N_EDGES_C 1250000
#define N_PAIRS_C 200000
#define IN_DIM_C 128
#define HID_C 64

// graph-build geometry
#define NB_S 256
#define BSH 9
#define NPB 512
#define NBKT 196
#define SEG_CAP 8192

// ---------------- scan helpers ----------------

#define SCAN_TPB 256
#define SCAN_IPT 4
#define SCAN_ELEMS 1024

__global__ void k_scan_partial(const int* __restrict__ in, int* __restrict__ outp,
                               int* __restrict__ blocksums, int n) {
    __shared__ int sd[SCAN_TPB];
    int tid = threadIdx.x;
    int base = blockIdx.x * SCAN_ELEMS + tid * SCAN_IPT;
    int v[SCAN_IPT]; int s = 0;
    for (int k = 0; k < SCAN_IPT; k++) { int idx = base + k; v[k] = (idx < n) ? in[idx] : 0; s += v[k]; }
    sd[tid] = s;
    __syncthreads();
    for (int off = 1; off < SCAN_TPB; off <<= 1) {
        int t = (tid >= off) ? sd[tid - off] : 0;
        __syncthreads();
        sd[tid] += t;
        __syncthreads();
    }
    int excl = sd[tid] - s;
    for (int k = 0; k < SCAN_IPT; k++) { int idx = base + k; if (idx < n) outp[idx] = excl; excl += v[k]; }
    if (tid == SCAN_TPB - 1) blocksums[blockIdx.x] = sd[tid];
}

__global__ void k_scan_blocks(int* __restrict__ bs, int nb) {
    __shared__ int sd[128];
    int t = threadIdx.x;
    int v = (t < nb) ? bs[t] : 0;
    sd[t] = v;
    __syncthreads();
    for (int off = 1; off < 128; off <<= 1) {
        int u = (t >= off) ? sd[t - off] : 0;
        __syncthreads();
        sd[t] += u;
        __syncthreads();
    }
    if (t < nb) bs[t] = sd[t] - v;
}

__global__ void k_scan_addg(int* __restrict__ arr, const int* __restrict__ bs, int n) {
    int i = blockIdx.x * blockDim.x + threadIdx.x;
    if (i < n) arr[i] += bs[i >> 10];
}

// ---------------- graph build: two-level counting sort ----------------

__global__ __launch_bounds__(256) void k_hist(const int* __restrict__ dst,
                                              int* __restrict__ histT, int e) {
    __shared__ int lh[NBKT];
    int tid = threadIdx.x, k = blockIdx.x;
    if (tid < NBKT) lh[tid] = 0;
    __syncthreads();
    int chunk = (e + NB_S - 1) / NB_S;
    int i0 = k * chunk, i1 = min(i0 + chunk, e);
    for (int i = i0 + tid; i < i1; i += 256) atomicAdd(&lh[dst[i] >> BSH], 1);
    __syncthreads();
    if (tid < NBKT) histT[tid * NB_S + k] = lh[tid];
}

__global__ __launch_bounds__(256) void k_scatter(const int* __restrict__ edges,
                                                 const int* __restrict__ offs,
                                                 int2* __restrict__ staging, int e) {
    __shared__ int cur[NBKT];
    int tid = threadIdx.x, k = blockIdx.x;
    if (tid < NBKT) cur[tid] = offs[tid * NB_S + k];
    __syncthreads();
    int chunk = (e + NB_S - 1) / NB_S;
    int i0 = k * chunk, i1 = min(i0 + chunk, e);
    for (int i = i0 + tid; i < i1; i += 256) {
        int s = edges[i];
        int d = edges[e + i];
        int p = atomicAdd(&cur[d >> BSH], 1);
        staging[p] = make_int2(s, d);
    }
}

__global__ __launch_bounds__(256) void k_bucket_fill(const int2* __restrict__ staging,
        const int* __restrict__ offs, int* __restrict__ rowptr,
        float* __restrict__ invd, int* __restrict__ adj, int n, int e) {
    __shared__ int ldeg[NPB];
    __shared__ int lrow[NPB];
    __shared__ int ps[256];
    __shared__ int lseg[SEG_CAP];
    int tid = threadIdx.x, b = blockIdx.x;
    int n0 = b << BSH;
    int nn = min(NPB, n - n0);
    int segBeg = offs[b * NB_S];
    int segEnd = (b == NBKT - 1) ? e : offs[(b + 1) * NB_S];

    ldeg[tid] = 0; ldeg[tid + 256] = 0;
    __syncthreads();
    for (int i = segBeg + tid; i < segEnd; i += 256)
        atomicAdd(&ldeg[staging[i].y - n0], 1);
    __syncthreads();

    int a0 = ldeg[2 * tid], a1 = ldeg[2 * tid + 1];
    int s = a0 + a1;
    ps[tid] = s;
    __syncthreads();
    for (int off = 1; off < 256; off <<= 1) {
        int t = (tid >= off) ? ps[tid - off] : 0;
        __syncthreads();
        ps[tid] += t;
        __syncthreads();
    }
    int excl = ps[tid] - s;
    lrow[2 * tid] = excl;
    lrow[2 * tid + 1] = excl + a0;
    __syncthreads();

    for (int j = tid; j < nn; j += 256) {
        rowptr[n0 + j] = segBeg + lrow[j];
        int d = ldeg[j];
        invd[n0 + j] = (d > 0) ? (1.0f / (float)d) : 0.0f;
    }
    if (b == NBKT - 1 && tid == 0) rowptr[n] = e;
    __syncthreads();

    for (int i = segBeg + tid; i < segEnd; i += 256) {
        int2 ed = staging[i];
        int p = atomicAdd(&lrow[ed.y - n0], 1);
        if (p < SEG_CAP) lseg[p] = ed.x;
        else adj[segBeg + p] = ed.x;
    }
    __syncthreads();

    int m = segEnd - segBeg; if (m > SEG_CAP) m = SEG_CAP;
    for (int p = tid; p < m; p += 256) adj[segBeg + p] = lseg[p];
}

// ---------------- aggregation ----------------

__global__ __launch_bounds__(256) void k_aggregate(const int* __restrict__ rowptr,
        const int* __restrict__ adj, const float* __restrict__ invd,
        const float* __restrict__ hin, float* __restrict__ agg, int n) {
    int wid = threadIdx.x >> 6, lane = threadIdx.x & 63;
    int node = blockIdx.x * 4 + wid;
    if (node >= n) return;
    int beg = rowptr[node], end = rowptr[node + 1];
    float acc = 0.0f;
    for (int e = beg; e < end; e += 8) {
        int idx[8];
        #pragma unroll
        for (int j = 0; j < 8; ++j) {
            int ee = e + j;
            idx[j] = adj[ee < end ? ee : end - 1];
        }
        float v[8];
        #pragma unroll
        for (int j = 0; j < 8; ++j) v[j] = hin[(size_t)idx[j] * HID_C + lane];
        #pragma unroll
        for (int j = 0; j < 8; ++j) acc += (e + j < end) ? v[j] : 0.0f;
    }
    agg[(size_t)node * HID_C + lane] = acc * invd[node];
}

// ---------------- tiled GEMM (64 rows x 64 cols, K=128, thread = 4x4 tile) ----
// R4 PROVEN ARTIFACT — byte-identical resubmission. 65 us pred GEMM, 44 MB
// fetch, VGPR 92, no scratch. Every deviation tried (R5-R8: register-direct A,
// two-half AT, launch_bounds(256,3/4)) triggered a hipcc scratch pathology
// (1.5-6.3 GB HBM scratch traffic per dispatch, VALUBusy ~1%). DO NOT MODIFY
// THIS KERNEL without an isolated single-variable probe.
// MODE 0: encoder  MODE 1: layer  MODE 2: pred (fused @W2+b2)

__device__ __forceinline__ float4 ld4(const float* p) { return *(const float4*)p; }

template<int MODE>
__global__ __launch_bounds__(256, 2) void k_gemm(
    const float* __restrict__ A1, const float* __restrict__ A2,
    const int* __restrict__ pidx,
    const float* __restrict__ Ws1, const float* __restrict__ Ws2,
    const float* __restrict__ bias, const float* __restrict__ W2p,
    const float* __restrict__ b2p,
    float* __restrict__ outp, int nrows)
{
    __shared__ float AT[128 * 64];   // 32 KB, transposed+swizzled
    __shared__ float Wm[128 * 64];   // 32 KB, k-major
    const int t = threadIdx.x;
    const int g0 = blockIdx.x * 64;

    #pragma unroll
    for (int p = 0; p < 8; ++p) {
        int k = p * 16 + (t >> 4);
        int c4 = (t & 15) * 4;
        float4 wv;
        if (MODE == 1) wv = (k < 64) ? ld4(Ws1 + k * 64 + c4) : ld4(Ws2 + (k - 64) * 64 + c4);
        else           wv = ld4(Ws1 + k * 64 + c4);
        *(float4*)&Wm[k * 64 + c4] = wv;
    }
    #pragma unroll
    for (int p = 0; p < 8; ++p) {
        int r = p * 8 + (t >> 5);
        int c = t & 31;
        int g = g0 + r; if (g > nrows - 1) g = nrows - 1;
        const float* ptr;
        if (MODE == 0)      ptr = A1 + (size_t)g * 128 + c * 4;
        else if (MODE == 1) ptr = (c < 16) ? (A1 + (size_t)g * 64 + c * 4)
                                           : (A2 + (size_t)g * 64 + (c - 16) * 4);
        else { int idx = pidx[2 * g + (c >> 4)]; ptr = A1 + (size_t)idx * 64 + (c & 15) * 4; }
        float4 av = ld4(ptr);
        int rs = r ^ ((c & 15) * 4);
        int base = c * 256 + rs;
        AT[base      ] = av.x;
        AT[base +  64] = av.y;
        AT[base + 128] = av.z;
        AT[base + 192] = av.w;
    }
    __syncthreads();

    const int tc = t & 15, tr = t >> 4;
    const int tc4 = tc * 4, tr4 = tr * 4;
    float4 acc0 = {0, 0, 0, 0}, acc1 = acc0, acc2 = acc0, acc3 = acc0;

    #pragma unroll 4
    for (int kc = 0; kc < 32; ++kc) {
        int abase = kc * 256 + (tr4 ^ ((kc & 15) * 4));
        int wbase = kc * 256 + tc4;
        #pragma unroll
        for (int i = 0; i < 4; ++i) {
            float4 aw = ld4(&AT[abase + i * 64]);
            float4 ww = ld4(&Wm[wbase + i * 64]);
            acc0.x = fmaf(aw.x, ww.x, acc0.x); acc0.y = fmaf(aw.x, ww.y, acc0.y);
            acc0.z = fmaf(aw.x, ww.z, acc0.z); acc0.w = fmaf(aw.x, ww.w, acc0.w);
            acc1.x = fmaf(aw.y, ww.x, acc1.x); acc1.y = fmaf(aw.y, ww.y, acc1.y);
            acc1.z = fmaf(aw.y, ww.z, acc1.z); acc1.w = fmaf(aw.y, ww.w, acc1.w);
            acc2.x = fmaf(aw.z, ww.x, acc2.x); acc2.y = fmaf(aw.z, ww.y, acc2.y);
            acc2.z = fmaf(aw.z, ww.z, acc2.z); acc2.w = fmaf(aw.z, ww.w, acc2.w);
            acc3.x = fmaf(aw.w, ww.x, acc3.x); acc3.y = fmaf(aw.w, ww.y, acc3.y);
            acc3.z = fmaf(aw.w, ww.z, acc3.z); acc3.w = fmaf(aw.w, ww.w, acc3.w);
        }
    }

    float4 bv = ld4(bias + tc4);
    float4 accs[4] = {acc0, acc1, acc2, acc3};
    if (MODE == 2) {
        float4 w2 = ld4(W2p + tc4);
        float bb = b2p[0];
        #pragma unroll
        for (int i = 0; i < 4; ++i) {
            float zx = fmaxf(accs[i].x + bv.x, 0.f);
            float zy = fmaxf(accs[i].y + bv.y, 0.f);
            float zz = fmaxf(accs[i].z + bv.z, 0.f);
            float zw = fmaxf(accs[i].w + bv.w, 0.f);
            float v = zx * w2.x + zy * w2.y + zz * w2.z + zw * w2.w;
            v += __shfl_down(v, 8, 64);
            v += __shfl_down(v, 4, 64);
            v += __shfl_down(v, 2, 64);
            v += __shfl_down(v, 1, 64);
            if (tc == 0) {
                int g = g0 + tr4 + i;
                if (g < nrows) outp[g] = v + bb;
            }
        }
    } else {
        #pragma unroll
        for (int i = 0; i < 4; ++i) {
            int g = g0 + tr4 + i;
            if (g < nrows) {
                float4 o;
                o.x = fmaxf(accs[i].x + bv.x, 0.f);
                o.y = fmaxf(accs[i].y + bv.y, 0.f);
                o.z = fmaxf(accs[i].z + bv.z, 0.f);
                o.w = fmaxf(accs[i].w + bv.w, 0.f);
                *(float4*)&outp[(size_t)g * 64 + tc4] = o;
            }
        }
    }
}

// keep <2> instantiated so modes 0/1 codegen context is unchanged (rule #19)
template __global__ void k_gemm<2>(
    const float* __restrict__, const float* __restrict__, const int* __restrict__,
    const float* __restrict__, const float* __restrict__, const float* __restrict__,
    const float* __restrict__, const float* __restrict__, float* __restrict__, int);

// ---------------- pred-path factorization ----------------
// z@W1 = (h@W1[:64])[a] + (h@W1[64:])[b].
// k_uv: UV GEMM, M=100k K=64 N=128 (U cols 0..63, V cols 64..127), 8x8 thread
// tile -> 1 B LDS per FLOP (2x better than the 4x4 k_gemm). K=64 staged once,
// no K-loop. A stored k-major with XOR swizzle sw=(k>>2)*4: staging writes are
// 2-way (free), compute a-reads hit 4 distinct banks (16-lane broadcast).

__device__ __forceinline__ void fma4(float4& acc, float sc, const float4& wv) {
    acc.x = fmaf(sc, wv.x, acc.x);
    acc.y = fmaf(sc, wv.y, acc.y);
    acc.z = fmaf(sc, wv.z, acc.z);
    acc.w = fmaf(sc, wv.w, acc.w);
}

__global__ __launch_bounds__(256, 2) void k_uv(
    const float* __restrict__ H, const float* __restrict__ W1,
    float* __restrict__ U, float* __restrict__ V, int nrows)
{
    __shared__ float AT[64 * 128];   // [k][row^sw], 32 KB
    __shared__ float Wm[64 * 128];   // [k][col],    32 KB
    const int t = threadIdx.x;
    const int g0 = blockIdx.x * 128;

    // stage Wc[k][j]: j<64 -> W1[k][j] (U half), else W1[64+k][j-64] (V half)
    #pragma unroll
    for (int p = 0; p < 8; ++p) {
        int li = p * 256 + t;          // 0..2047
        int k = li >> 5;               // 0..63
        int j4 = (li & 31) * 4;        // 0..124
        float4 wv = (j4 < 64) ? ld4(W1 + k * 64 + j4)
                              : ld4(W1 + (64 + k) * 64 + (j4 - 64));
        *(float4*)&Wm[k * 128 + j4] = wv;
    }
    // stage A transposed + swizzled: AT[k][r ^ ((k>>2)*4)] = H[g0+r][k]
    #pragma unroll
    for (int p = 0; p < 8; ++p) {
        int li = p * 256 + t;          // 128 rows x 16 col4-groups
        int r = li >> 4;               // 0..127
        int c4 = (li & 15) * 4;        // 0..60
        int g = g0 + r; if (g > nrows - 1) g = nrows - 1;
        float4 av = ld4(H + (size_t)g * 64 + c4);
        AT[(c4    ) * 128 + (r ^ (((c4    ) >> 2) * 4))] = av.x;
        AT[(c4 + 1) * 128 + (r ^ (((c4 + 1) >> 2) * 4))] = av.y;
        AT[(c4 + 2) * 128 + (r ^ (((c4 + 2) >> 2) * 4))] = av.z;
        AT[(c4 + 3) * 128 + (r ^ (((c4 + 3) >> 2) * 4))] = av.w;
    }
    __syncthreads();

    const int tc = t & 15, tr = t >> 4;
    const int c0 = tc * 4;             // U cols c0..c0+3, V cols 64+c0..+3
    const int r0 = tr * 8;             // rows r0..r0+7
    float4 accA[8], accB[8];
    #pragma unroll
    for (int i = 0; i < 8; ++i) {
        accA[i] = make_float4(0.f, 0.f, 0.f, 0.f);
        accB[i] = make_float4(0.f, 0.f, 0.f, 0.f);
    }

    #pragma unroll 4
    for (int k = 0; k < 64; ++k) {
        const float* arow = &AT[k * 128];
        int sw = (k >> 2) * 4;
        float4 a0 = ld4(arow + ((r0    ) ^ sw));   // rows r0..r0+3 at this k
        float4 a1 = ld4(arow + ((r0 + 4) ^ sw));   // rows r0+4..r0+7
        float4 w0 = ld4(&Wm[k * 128 + c0]);        // U cols
        float4 w1 = ld4(&Wm[k * 128 + 64 + c0]);   // V cols
        fma4(accA[0], a0.x, w0); fma4(accB[0], a0.x, w1);
        fma4(accA[1], a0.y, w0); fma4(accB[1], a0.y, w1);
        fma4(accA[2], a0.z, w0); fma4(accB[2], a0.z, w1);
        fma4(accA[3], a0.w, w0); fma4(accB[3], a0.w, w1);
        fma4(accA[4], a1.x, w0); fma4(accB[4], a1.x, w1);
        fma4(accA[5], a1.y, w0); fma4(accB[5], a1.y, w1);
        fma4(accA[6], a1.z, w0); fma4(accB[6], a1.z, w1);
        fma4(accA[7], a1.w, w0); fma4(accB[7], a1.w, w1);
    }

    #pragma unroll
    for (int i = 0; i < 8; ++i) {
        int g = g0 + r0 + i;
        if (g < nrows) {
            *(float4*)&U[(size_t)g * 64 + c0] = accA[i];
            *(float4*)&V[(size_t)g * 64 + c0] = accB[i];
        }
    }
}

// k_pred: out[p] = relu(U[a] + V[b] + b1) . W2 + b2 — pure gather-reduce.
// 16 lanes per pair, 256 B coalesced row per gather, shfl-reduce width 16.
__global__ __launch_bounds__(256) void k_pred(
    const float* __restrict__ U, const float* __restrict__ V,
    const int* __restrict__ pidx, const float* __restrict__ b1,
    const float* __restrict__ W2, const float* __restrict__ b2,
    float* __restrict__ outp, int np)
{
    const int t = threadIdx.x;
    const int lg = t & 15;
    const int p = blockIdx.x * 16 + (t >> 4);
    float4 bv = ld4(b1 + lg * 4);
    float4 wv = ld4(W2 + lg * 4);
    if (p >= np) return;
    int2 ab = ((const int2*)pidx)[p];
    float4 u = ld4(U + (size_t)ab.x * 64 + lg * 4);
    float4 v = ld4(V + (size_t)ab.y * 64 + lg * 4);
    float zx = fmaxf(u.x + v.x + bv.x, 0.f);
    float zy = fmaxf(u.y + v.y + bv.y, 0.f);
    float zz = fmaxf(u.z + v.z + bv.z, 0.f);
    float zw = fmaxf(u.w + v.w + bv.w, 0.f);
    float s = zx * wv.x + zy * wv.y + zz * wv.z + zw * wv.w;
    s += __shfl_down(s, 8, 16);
    s += __shfl_down(s, 4, 16);
    s += __shfl_down(s, 2, 16);
    s += __shfl_down(s, 1, 16);
    if (lg == 0) outp[p] = s + b2[0];
}

// ---------------- launch ----------------

extern "C" void kernel_launch(void* const* d_in, const int* in_sizes, int n_in,
                              void* d_out, int out_size, void* d_ws, size_t ws_size,
                              hipStream_t stream) {
    const float* x    = (const float*)d_in[0];
    const int*   edges= (const int*)d_in[1];
    const int*   pair = (const int*)d_in[2];
    const float* encW = (const float*)d_in[3];
    const float* encb = (const float*)d_in[4];
    const float* Wl   = (const float*)d_in[5];
    const float* bl   = (const float*)d_in[6];
    const float* Wr   = (const float*)d_in[7];
    const float* W1   = (const float*)d_in[8];
    const float* b1   = (const float*)d_in[9];
    const float* W2   = (const float*)d_in[10];
    const float* b2   = (const float*)d_in[11];
    float* out = (float*)d_out;

    const int N = N_NODES_C, E = N_EDGES_C, P = N_PAIRS_C;
    const int* dst = edges + E;
    const int M = NBKT * NB_S;

    char* w = (char*)d_ws;
    auto alloc = [&](size_t bytes) { char* p = w; w += (bytes + 255) & ~(size_t)255; return p; };
    int*   rowptr = (int*)alloc((size_t)(N + 1) * 4);
    int*   histT  = (int*)alloc((size_t)M * 4);
    int*   offs   = (int*)alloc((size_t)M * 4);
    int*   bsums  = (int*)alloc(128 * 4);
    float* invd   = (float*)alloc((size_t)N * 4);
    int*   adj    = (int*)alloc((size_t)E * 4);
    float* h0     = (float*)alloc((size_t)N * HID_C * 4);
    float* h1     = (float*)alloc((size_t)N * HID_C * 4);
    float* agg    = (float*)alloc((size_t)N * HID_C * 4);
    int2*  staging= (int2*)agg;

    int nscan = (M + SCAN_ELEMS - 1) / SCAN_ELEMS;

    hipLaunchKernelGGL(k_hist, dim3(NB_S), dim3(256), 0, stream, dst, histT, E);
    hipLaunchKernelGGL(k_scan_partial, dim3(nscan), dim3(SCAN_TPB), 0, stream, histT, offs, bsums, M);
    hipLaunchKernelGGL(k_scan_blocks, dim3(1), dim3(128), 0, stream, bsums, nscan);
    hipLaunchKernelGGL(k_scan_addg, dim3((M + 255) / 256), dim3(256), 0, stream, offs, bsums, M);
    hipLaunchKernelGGL(k_scatter, dim3(NB_S), dim3(256), 0, stream, edges, offs, staging, E);
    hipLaunchKernelGGL(k_bucket_fill, dim3(NBKT), dim3(256), 0, stream, staging, offs, rowptr, invd, adj, N, E);

    const int NB_N = (N + 63) / 64;

    k_gemm<0><<<dim3(NB_N), dim3(256), 0, stream>>>(
        x, nullptr, nullptr, encW, nullptr, encb, nullptr, nullptr, h0, N);

    float* hc = h0; float* hn = h1;
    for (int l = 0; l < 3; l++) {
        hipLaunchKernelGGL(k_aggregate, dim3((N + 3) / 4), dim3(256), 0, stream,
                           rowptr, adj, invd, hc, agg, N);
        k_gemm<1><<<dim3(NB_N), dim3(256), 0, stream>>>(
            agg, hc, nullptr, Wl + (size_t)l * 64 * 64, Wr + (size_t)l * 64 * 64,
            bl + (size_t)l * 64, nullptr, nullptr, hn, N);
        float* tswap = hc; hc = hn; hn = tswap;
    }

    // pred path: UV = h @ [W1_top | W1_bot], then per-pair gather-reduce.
    // U reuses agg (staging long dead), V reuses the retired h buffer (hn).
    float* Ubuf = agg;
    float* Vbuf = hn;
    const int NB_UV = (N + 127) / 128;
    hipLaunchKernelGGL(k_uv, dim3(NB_UV), dim3(256), 0, stream, hc, W1, Ubuf, Vbuf, N);
    hipLaunchKernelGGL(k_pred, dim3((P + 15) / 16), dim3(256), 0, stream,
                       Ubuf, Vbuf, pair, b1, W2, b2, out, P);
}